// Round 4
// baseline (294.245 us; speedup 1.0000x reference)
//
#include <hip/hip_runtime.h>

#define Bb 4
#define Nn 2048
#define Dd 1024
#define Rr 64
#define LN_EPS 1e-5f

typedef unsigned short u16;
typedef short bf16x8 __attribute__((ext_vector_type(8)));   // 8 bf16 in 4 VGPRs
typedef u16 u16x4v __attribute__((ext_vector_type(4)));
typedef float f32x4 __attribute__((ext_vector_type(4)));

__device__ __forceinline__ u16 f2bf(float f) {
  unsigned u = __float_as_uint(f);
  u += 0x7FFFu + ((u >> 16) & 1u);   // RNE
  return (u16)(u >> 16);
}

// ---- prep_x: x (B,N,D) f32 -> xt (B,D,N) bf16 (transposed for PV B-operand) ----
__global__ __launch_bounds__(256) void prep_x(const float* __restrict__ x,
                                              u16* __restrict__ xt) {
  __shared__ float tile[64][65];
  const int b = blockIdx.z;
  const int n0 = blockIdx.x * 64;
  const int d0 = blockIdx.y * 64;
  const int t = threadIdx.x;
  const int c = t & 63, r4 = t >> 6;
#pragma unroll
  for (int rr = 0; rr < 16; rr++) {
    int row = rr * 4 + r4;
    tile[row][c] = x[(size_t)(b * Nn + n0 + row) * Dd + d0 + c];
  }
  __syncthreads();
#pragma unroll
  for (int rr = 0; rr < 16; rr++) {
    int dd = rr * 4 + r4;
    xt[(size_t)(b * Dd + d0 + dd) * Nn + n0 + c] = f2bf(tile[c][dd]);
  }
}

// ---- prep_small: fuses prep_uv (blocks 0..31) and qscale (blocks 32..2079) ----
__global__ __launch_bounds__(256) void prep_small(const float* __restrict__ U,
    const float* __restrict__ V, const float* __restrict__ mask,
    u16* __restrict__ uvt, float* __restrict__ qs) {
  if (blockIdx.x < 32) {
    __shared__ float tile[64][65];
    const int which = blockIdx.x >> 4;
    const int d0 = (blockIdx.x & 15) * 64;
    const float* src = which ? V : U;
    const int t = threadIdx.x, c = t & 63, r4 = t >> 6;
#pragma unroll
    for (int rr = 0; rr < 16; rr++) {
      int row = rr * 4 + r4;
      tile[row][c] = src[(size_t)(d0 + row) * Rr + c];
    }
    __syncthreads();
#pragma unroll
    for (int rr = 0; rr < 16; rr++) {
      int r = rr * 4 + r4;
      uvt[(size_t)(which * 64 + r) * Dd + d0 + c] = f2bf(tile[c][r]);
    }
  } else {
    const int row = (blockIdx.x - 32) * 4 + (threadIdx.x >> 6);
    const int lane = threadIdx.x & 63;
    float v = mask[(size_t)row * Rr + lane];
#pragma unroll
    for (int off = 32; off; off >>= 1) v += __shfl_xor(v, off);
    if (lane == 0) qs[row] = rsqrtf(fmaxf(v, 1.0f));
  }
}

// ---- proj_qk: Q = (x@U)*mask, K = (x@V)*mask, bf16 out. 64 rows x 128 cols/block ----
__global__ __launch_bounds__(256) void proj_qk(const float* __restrict__ x,
    const float* __restrict__ mask, const u16* __restrict__ uvt,
    u16* __restrict__ Qo, u16* __restrict__ Ko) {
  const int t = threadIdx.x;
  const int w = t >> 6, l = t & 63, quad = l >> 4, l16 = l & 15;
  const int g0 = blockIdx.x * 64;
  f32x4 acc[4][2];
#pragma unroll
  for (int i = 0; i < 4; i++)
#pragma unroll
    for (int j = 0; j < 2; j++) acc[i][j] = (f32x4){0.f, 0.f, 0.f, 0.f};
  for (int k0 = 0; k0 < Dd; k0 += 32) {
    bf16x8 a[4];
#pragma unroll
    for (int mt = 0; mt < 4; mt++) {
      const float4* px = (const float4*)&x[(size_t)(g0 + mt * 16 + l16) * Dd + k0 + quad * 8];
      float4 x0 = px[0], x1 = px[1];
      bf16x8 av;
      av[0] = (short)f2bf(x0.x); av[1] = (short)f2bf(x0.y);
      av[2] = (short)f2bf(x0.z); av[3] = (short)f2bf(x0.w);
      av[4] = (short)f2bf(x1.x); av[5] = (short)f2bf(x1.y);
      av[6] = (short)f2bf(x1.z); av[7] = (short)f2bf(x1.w);
      a[mt] = av;
    }
    bf16x8 bfr[2];
#pragma unroll
    for (int i = 0; i < 2; i++) {
      int col = (w * 2 + i) * 16 + l16;
      bfr[i] = *(const bf16x8*)&uvt[(size_t)col * Dd + k0 + quad * 8];
    }
#pragma unroll
    for (int mt = 0; mt < 4; mt++)
#pragma unroll
      for (int i = 0; i < 2; i++)
        acc[mt][i] = __builtin_amdgcn_mfma_f32_16x16x32_bf16(a[mt], bfr[i], acc[mt][i], 0, 0, 0);
  }
#pragma unroll
  for (int mt = 0; mt < 4; mt++)
#pragma unroll
    for (int i = 0; i < 2; i++) {
      int col = (w * 2 + i) * 16 + l16;
      int r_ = col & 63;
#pragma unroll
      for (int r = 0; r < 4; r++) {
        int row = g0 + mt * 16 + quad * 4 + r;
        float v = acc[mt][i][r] * mask[(size_t)row * Rr + r_];
        u16 bv = f2bf(v);
        if (col < 64) Qo[(size_t)row * Rr + r_] = bv;
        else          Ko[(size_t)row * Rr + r_] = bv;
      }
    }
}

// ---- attn: flash-style, D-SPLIT for occupancy (R3).
// Block = 32 queries x 512 D-half, 8 waves; wave w: S-tile (m=w&1, n=w>>1),
// PV D-chunk = dh*512 + w*64. Per-wave state halved vs R2 (acc 32f, xf 8 frags)
// so VGPR<=128 -> 4 waves/SIMD; grid 512 -> 2 independent blocks/CU whose
// barriers decouple (R2 was 1 block/CU, 22% occ, latency-bound at 11.7k cyc/iter).
// QK+softmax duplicated across the 2 D-half blocks (cheap). Writes y=x+delta to
// d_out; LN done by ln_k in-place after.
// Swizzle: xcd=id&7 -> (batch=xcd>>1, dh=xcd&1): each XCD touches one 2 MB
// Xt half-slice (L2-resident).
__global__ __launch_bounds__(512, 4) void attn(const float* __restrict__ x,
    const u16* __restrict__ xt, const u16* __restrict__ Qm,
    const u16* __restrict__ Km, const float* __restrict__ qs,
    float* __restrict__ y) {
  __shared__ float s_lds[32][65];
  __shared__ __align__(16) u16 p_lds[32][72];
  __shared__ float m_lds[32], l_lds[32], al_lds[32], qs_lds[32];
  const int t = threadIdx.x;
  const int w = t >> 6, l = t & 63, quad = l >> 4, l16 = l & 15;
  const int id = blockIdx.x;
  const int xcd = id & 7;
  const int b = xcd >> 1;
  const int dh = xcd & 1;
  const int q0 = (id >> 3) * 32;
  const int d0 = dh * 512 + w * 64;          // this wave's D-chunk base
  const size_t xbase = (size_t)b * Nn * Dd;
  const int mw = w & 1, nw = w >> 1;
  bf16x8 qf[2];
#pragma unroll
  for (int ks = 0; ks < 2; ks++)
    qf[ks] = *(const bf16x8*)&Qm[(size_t)(b * Nn + q0 + mw * 16 + l16) * Rr + ks * 32 + quad * 8];
  bf16x8 kf[2];
#pragma unroll
  for (int ks = 0; ks < 2; ks++)
    kf[ks] = *(const bf16x8*)&Km[(size_t)(b * Nn + 0 + nw * 16 + l16) * Rr + ks * 32 + quad * 8];
  if (t < 32) {
    m_lds[t] = -1e30f; l_lds[t] = 0.f;
    qs_lds[t] = qs[(size_t)b * Nn + q0 + t];
  }
  f32x4 acc[2][4];
#pragma unroll
  for (int i = 0; i < 2; i++)
#pragma unroll
    for (int j = 0; j < 4; j++) acc[i][j] = (f32x4){0.f, 0.f, 0.f, 0.f};
  __syncthreads();
#pragma unroll 1
  for (int kt = 0; kt < Nn / 64; kt++) {
    const int k0 = kt * 64;
    // ---- issue this iteration's 8 Xt frag loads up front ----
    bf16x8 xf[8];
#pragma unroll
    for (int ks = 0; ks < 2; ks++)
#pragma unroll
      for (int nt = 0; nt < 4; nt++)
        xf[ks * 4 + nt] = *(const bf16x8*)&xt[(size_t)(b * Dd + d0 + nt * 16 + l16) * Nn + k0 + ks * 32 + quad * 8];
    // ---- prefetch next iteration's K-frags ----
    const int k0n = (kt < Nn / 64 - 1) ? k0 + 64 : 0;
    bf16x8 kf_n[2];
#pragma unroll
    for (int ks = 0; ks < 2; ks++)
      kf_n[ks] = *(const bf16x8*)&Km[(size_t)(b * Nn + k0n + nw * 16 + l16) * Rr + ks * 32 + quad * 8];
    // ---- S = Q K^T ----
    f32x4 s = (f32x4){0.f, 0.f, 0.f, 0.f};
#pragma unroll
    for (int ks = 0; ks < 2; ks++)
      s = __builtin_amdgcn_mfma_f32_16x16x32_bf16(qf[ks], kf[ks], s, 0, 0, 0);
#pragma unroll
    for (int r = 0; r < 4; r++)
      s_lds[mw * 16 + quad * 4 + r][nw * 16 + l16] = s[r];
    __syncthreads();
    // ---- online softmax (row = t>>4, 16 threads/row, 4 cols each) ----
    {
      const int row = t >> 4, sub = t & 15;
      const float sc = qs_lds[row];
      float v0 = s_lds[row][sub * 4 + 0] * sc;
      float v1 = s_lds[row][sub * 4 + 1] * sc;
      float v2 = s_lds[row][sub * 4 + 2] * sc;
      float v3 = s_lds[row][sub * 4 + 3] * sc;
      float mx = fmaxf(fmaxf(v0, v1), fmaxf(v2, v3));
#pragma unroll
      for (int off = 1; off < 16; off <<= 1) mx = fmaxf(mx, __shfl_xor(mx, off));
      const float m_old = m_lds[row];          // same-wave read-before-write
      const float m_new = fmaxf(m_old, mx);
      float p0 = __expf(v0 - m_new), p1 = __expf(v1 - m_new);
      float p2 = __expf(v2 - m_new), p3 = __expf(v3 - m_new);
      float rs = p0 + p1 + p2 + p3;
#pragma unroll
      for (int off = 1; off < 16; off <<= 1) rs += __shfl_xor(rs, off);
      const float alpha = __expf(m_old - m_new);
      if (sub == 0) {
        m_lds[row] = m_new;
        l_lds[row] = l_lds[row] * alpha + rs;
        al_lds[row] = alpha;
      }
      u16x4v pk;
      pk[0] = f2bf(p0); pk[1] = f2bf(p1); pk[2] = f2bf(p2); pk[3] = f2bf(p3);
      *(u16x4v*)&p_lds[row][sub * 4] = pk;
    }
    __syncthreads();
    // ---- rescale O, then O += P @ X ----
    float alr[2][4];
#pragma unroll
    for (int mt = 0; mt < 2; mt++)
#pragma unroll
      for (int r = 0; r < 4; r++) alr[mt][r] = al_lds[mt * 16 + quad * 4 + r];
#pragma unroll
    for (int mt = 0; mt < 2; mt++)
#pragma unroll
      for (int nt = 0; nt < 4; nt++)
#pragma unroll
        for (int r = 0; r < 4; r++) acc[mt][nt][r] *= alr[mt][r];
#pragma unroll
    for (int ks = 0; ks < 2; ks++) {
      bf16x8 af[2];
#pragma unroll
      for (int mt = 0; mt < 2; mt++)
        af[mt] = *(const bf16x8*)&p_lds[mt * 16 + l16][ks * 32 + quad * 8];
#pragma unroll
      for (int nt = 0; nt < 4; nt++) {
#pragma unroll
        for (int mt = 0; mt < 2; mt++)
          acc[mt][nt] = __builtin_amdgcn_mfma_f32_16x16x32_bf16(af[mt], xf[ks * 4 + nt], acc[mt][nt], 0, 0, 0);
      }
    }
    kf[0] = kf_n[0]; kf[1] = kf_n[1];
  }
  // ---- epilogue: y = x + delta (f32) ; LN happens in ln_k ----
  float linv[2][4];
#pragma unroll
  for (int mt = 0; mt < 2; mt++)
#pragma unroll
    for (int r = 0; r < 4; r++) linv[mt][r] = 1.f / l_lds[mt * 16 + quad * 4 + r];
#pragma unroll
  for (int mt = 0; mt < 2; mt++)
#pragma unroll
    for (int nt = 0; nt < 4; nt++) {
      const int col = d0 + nt * 16 + l16;
#pragma unroll
      for (int r = 0; r < 4; r++) {
        const int row = q0 + mt * 16 + quad * 4 + r;
        y[xbase + (size_t)row * Dd + col] =
            x[xbase + (size_t)row * Dd + col] + acc[mt][nt][r] * linv[mt][r];
      }
    }
}

// ---- ln_k: in-place row-wise LayerNorm over d_out. 1 block (256 thr) per row ----
__global__ __launch_bounds__(256) void ln_k(float* __restrict__ y,
    const float* __restrict__ gamma, const float* __restrict__ beta) {
  __shared__ float rs[4], rq[4];
  const int row = blockIdx.x;
  const int t = threadIdx.x;
  float* p = y + (size_t)row * Dd;
  float4 v = ((const float4*)p)[t];
  float s = v.x + v.y + v.z + v.w;
  float q = v.x * v.x + v.y * v.y + v.z * v.z + v.w * v.w;
#pragma unroll
  for (int off = 32; off; off >>= 1) {
    s += __shfl_xor(s, off);
    q += __shfl_xor(q, off);
  }
  if ((t & 63) == 0) { rs[t >> 6] = s; rq[t >> 6] = q; }
  __syncthreads();
  float S = rs[0] + rs[1] + rs[2] + rs[3];
  float Q2 = rq[0] + rq[1] + rq[2] + rq[3];
  float mu = S * (1.f / Dd);
  float var = Q2 * (1.f / Dd) - mu * mu;
  float rstd = rsqrtf(var + LN_EPS);
  float4 g = ((const float4*)gamma)[t];
  float4 be = ((const float4*)beta)[t];
  v.x = (v.x - mu) * rstd * g.x + be.x;
  v.y = (v.y - mu) * rstd * g.y + be.y;
  v.z = (v.z - mu) * rstd * g.z + be.z;
  v.w = (v.w - mu) * rstd * g.w + be.w;
  ((float4*)p)[t] = v;
}

extern "C" void kernel_launch(void* const* d_in, const int* in_sizes, int n_in,
                              void* d_out, int out_size, void* d_ws, size_t ws_size,
                              hipStream_t stream) {
  const float* x     = (const float*)d_in[0];
  const float* mask  = (const float*)d_in[1];
  const float* U     = (const float*)d_in[2];
  const float* V     = (const float*)d_in[3];
  const float* gamma = (const float*)d_in[4];
  const float* beta  = (const float*)d_in[5];
  float* out = (float*)d_out;
  char* ws = (char*)d_ws;
  // workspace layout (~18.3 MB total)
  u16*   xt  = (u16*)ws;                                  // 16 MB  (B,D,N) bf16
  u16*   Qw  = (u16*)(ws + (size_t)(16 << 20));           // 1 MB
  u16*   Kw  = (u16*)(ws + (size_t)(17 << 20));           // 1 MB
  u16*   uvt = (u16*)(ws + (size_t)(18 << 20));           // 256 KB
  float* qsb = (float*)(ws + (size_t)(18 << 20) + (256 << 10)); // 32 KB

  prep_x    <<<dim3(Nn / 64, Dd / 64, Bb), 256, 0, stream>>>(x, xt);
  prep_small<<<32 + (Bb * Nn) / 4, 256, 0, stream>>>(U, V, mask, uvt, qsb);
  proj_qk   <<<(Bb * Nn) / 64, 256, 0, stream>>>(x, mask, uvt, Qw, Kw);
  attn      <<<512, 512, 0, stream>>>(x, xt, Qw, Kw, qsb, out);
  ln_k      <<<Bb * Nn, 256, 0, stream>>>(out, gamma, beta);
}

// Round 5
// 218.102 us; speedup vs baseline: 1.3491x; 1.3491x over previous
//
#include <hip/hip_runtime.h>

#define Bb 4
#define Nn 2048
#define Dd 1024
#define Rr 64
#define LN_EPS 1e-5f

typedef unsigned short u16;
typedef short bf16x8 __attribute__((ext_vector_type(8)));   // 8 bf16 in 4 VGPRs
typedef float f32x4 __attribute__((ext_vector_type(4)));

__device__ __forceinline__ u16 f2bf(float f) {
  unsigned u = __float_as_uint(f);
  u += 0x7FFFu + ((u >> 16) & 1u);   // RNE
  return (u16)(u >> 16);
}

// async global->LDS, 16 B per lane. LDS dest is wave-uniform base + lane*16.
__device__ __forceinline__ void g2l16(u16* l, const u16* g) {
  __builtin_amdgcn_global_load_lds(
      (const __attribute__((address_space(1))) unsigned int*)g,
      (__attribute__((address_space(3))) unsigned int*)l, 16, 0, 0);
}

// ---- prep_x: x (B,N,D) f32 -> xt (B,D,N) bf16 (d-major, PV/pv_gemm B-operand) ----
__global__ __launch_bounds__(256) void prep_x(const float* __restrict__ x,
                                              u16* __restrict__ xt) {
  __shared__ float tile[64][65];
  const int b = blockIdx.z;
  const int n0 = blockIdx.x * 64;
  const int d0 = blockIdx.y * 64;
  const int t = threadIdx.x;
  const int c = t & 63, r4 = t >> 6;
#pragma unroll
  for (int rr = 0; rr < 16; rr++) {
    int row = rr * 4 + r4;
    tile[row][c] = x[(size_t)(b * Nn + n0 + row) * Dd + d0 + c];
  }
  __syncthreads();
#pragma unroll
  for (int rr = 0; rr < 16; rr++) {
    int dd = rr * 4 + r4;
    xt[(size_t)(b * Dd + d0 + dd) * Nn + n0 + c] = f2bf(tile[c][dd]);
  }
}

// ---- prep_small: fuses prep_uv (blocks 0..31) and qscale (blocks 32..2079) ----
__global__ __launch_bounds__(256) void prep_small(const float* __restrict__ U,
    const float* __restrict__ V, const float* __restrict__ mask,
    u16* __restrict__ uvt, float* __restrict__ qs) {
  if (blockIdx.x < 32) {
    __shared__ float tile[64][65];
    const int which = blockIdx.x >> 4;
    const int d0 = (blockIdx.x & 15) * 64;
    const float* src = which ? V : U;
    const int t = threadIdx.x, c = t & 63, r4 = t >> 6;
#pragma unroll
    for (int rr = 0; rr < 16; rr++) {
      int row = rr * 4 + r4;
      tile[row][c] = src[(size_t)(d0 + row) * Rr + c];
    }
    __syncthreads();
#pragma unroll
    for (int rr = 0; rr < 16; rr++) {
      int r = rr * 4 + r4;
      uvt[(size_t)(which * 64 + r) * Dd + d0 + c] = f2bf(tile[c][r]);
    }
  } else {
    const int row = (blockIdx.x - 32) * 4 + (threadIdx.x >> 6);
    const int lane = threadIdx.x & 63;
    float v = mask[(size_t)row * Rr + lane];
#pragma unroll
    for (int off = 32; off; off >>= 1) v += __shfl_xor(v, off);
    if (lane == 0) qs[row] = rsqrtf(fmaxf(v, 1.0f));
  }
}

// ---- proj_qk: Q = (x@U)*mask, K = (x@V)*mask, bf16 out. 64 rows x 128 cols/block ----
__global__ __launch_bounds__(256) void proj_qk(const float* __restrict__ x,
    const float* __restrict__ mask, const u16* __restrict__ uvt,
    u16* __restrict__ Qo, u16* __restrict__ Ko) {
  const int t = threadIdx.x;
  const int w = t >> 6, l = t & 63, quad = l >> 4, l16 = l & 15;
  const int g0 = blockIdx.x * 64;
  f32x4 acc[4][2];
#pragma unroll
  for (int i = 0; i < 4; i++)
#pragma unroll
    for (int j = 0; j < 2; j++) acc[i][j] = (f32x4){0.f, 0.f, 0.f, 0.f};
  for (int k0 = 0; k0 < Dd; k0 += 32) {
    bf16x8 a[4];
#pragma unroll
    for (int mt = 0; mt < 4; mt++) {
      const float4* px = (const float4*)&x[(size_t)(g0 + mt * 16 + l16) * Dd + k0 + quad * 8];
      float4 x0 = px[0], x1 = px[1];
      bf16x8 av;
      av[0] = (short)f2bf(x0.x); av[1] = (short)f2bf(x0.y);
      av[2] = (short)f2bf(x0.z); av[3] = (short)f2bf(x0.w);
      av[4] = (short)f2bf(x1.x); av[5] = (short)f2bf(x1.y);
      av[6] = (short)f2bf(x1.z); av[7] = (short)f2bf(x1.w);
      a[mt] = av;
    }
    bf16x8 bfr[2];
#pragma unroll
    for (int i = 0; i < 2; i++) {
      int col = (w * 2 + i) * 16 + l16;
      bfr[i] = *(const bf16x8*)&uvt[(size_t)col * Dd + k0 + quad * 8];
    }
#pragma unroll
    for (int mt = 0; mt < 4; mt++)
#pragma unroll
      for (int i = 0; i < 2; i++)
        acc[mt][i] = __builtin_amdgcn_mfma_f32_16x16x32_bf16(a[mt], bfr[i], acc[mt][i], 0, 0, 0);
  }
#pragma unroll
  for (int mt = 0; mt < 4; mt++)
#pragma unroll
    for (int i = 0; i < 2; i++) {
      int col = (w * 2 + i) * 16 + l16;
      int r_ = col & 63;
#pragma unroll
      for (int r = 0; r < 4; r++) {
        int row = g0 + mt * 16 + quad * 4 + r;
        float v = acc[mt][i][r] * mask[(size_t)row * Rr + r_];
        u16 bv = f2bf(v);
        if (col < 64) Qo[(size_t)row * Rr + r_] = bv;
        else          Ko[(size_t)row * Rr + r_] = bv;
      }
    }
}

// ---- score_softmax (R4): block = 32 q-rows x ALL 2048 keys, 8 waves.
// Wave w owns key chunk [w*256, w*256+256): acc 32x256 (128 VGPR). K=64 inner
// (2 MFMA k-steps). Whole-row softmax ONCE per block (no barrier-locked inner
// loop — the R1-R3 flash structure was latency-bound at ~12k cyc/iter).
// Writes P = exp(v - rowmax) bf16 (unnormalized) and linv = 1/rowsum.
__global__ __launch_bounds__(512, 2) void score_softmax(
    const u16* __restrict__ Qm, const u16* __restrict__ Km,
    const float* __restrict__ qs, u16* __restrict__ Pw,
    float* __restrict__ linv_g) {
  __shared__ float red[32][8];
  __shared__ float mfin[32];
  const int t = threadIdx.x;
  const int w = t >> 6, l = t & 63, quad = l >> 4, l16 = l & 15;
  const int id = blockIdx.x;
  const int xcd = id & 7;
  const int b = xcd >> 1;
  const int q0 = (((id >> 3) << 1) | (xcd & 1)) * 32;
  // Q fragments (A-operand, 32x64): qf[mt][ks]
  bf16x8 qf[2][2];
#pragma unroll
  for (int mt = 0; mt < 2; mt++)
#pragma unroll
    for (int ks = 0; ks < 2; ks++)
      qf[mt][ks] = *(const bf16x8*)&Qm[(size_t)(b * Nn + q0 + mt * 16 + l16) * Rr + ks * 32 + quad * 8];
  // ---- S = Q K^T over this wave's 256 keys ----
  f32x4 acc[2][16];
#pragma unroll
  for (int mt = 0; mt < 2; mt++)
#pragma unroll
    for (int nt = 0; nt < 16; nt++) acc[mt][nt] = (f32x4){0.f, 0.f, 0.f, 0.f};
#pragma unroll
  for (int nt = 0; nt < 16; nt++) {
#pragma unroll
    for (int ks = 0; ks < 2; ks++) {
      bf16x8 kf = *(const bf16x8*)&Km[(size_t)(b * Nn + w * 256 + nt * 16 + l16) * Rr + ks * 32 + quad * 8];
#pragma unroll
      for (int mt = 0; mt < 2; mt++)
        acc[mt][nt] = __builtin_amdgcn_mfma_f32_16x16x32_bf16(qf[mt][ks], kf, acc[mt][nt], 0, 0, 0);
    }
  }
  // ---- scale by per-query 1/sqrt(r_eff) ----
  float sc[2][4];
#pragma unroll
  for (int mt = 0; mt < 2; mt++)
#pragma unroll
    for (int r = 0; r < 4; r++)
      sc[mt][r] = qs[(size_t)b * Nn + q0 + mt * 16 + quad * 4 + r];
#pragma unroll
  for (int mt = 0; mt < 2; mt++)
#pragma unroll
    for (int nt = 0; nt < 16; nt++)
#pragma unroll
      for (int r = 0; r < 4; r++) acc[mt][nt][r] *= sc[mt][r];
  // ---- row max: in-reg over nt, shuffle over l16, LDS across 8 waves ----
  float vmax[2][4];
#pragma unroll
  for (int mt = 0; mt < 2; mt++)
#pragma unroll
    for (int r = 0; r < 4; r++) {
      float m = -1e30f;
#pragma unroll
      for (int nt = 0; nt < 16; nt++) m = fmaxf(m, acc[mt][nt][r]);
#pragma unroll
      for (int off = 1; off < 16; off <<= 1) m = fmaxf(m, __shfl_xor(m, off));
      vmax[mt][r] = m;
    }
  if (l16 == 0) {
#pragma unroll
    for (int mt = 0; mt < 2; mt++)
#pragma unroll
      for (int r = 0; r < 4; r++) red[mt * 16 + quad * 4 + r][w] = vmax[mt][r];
  }
  __syncthreads();
  if (t < 32) {
    float m = -1e30f;
#pragma unroll
    for (int i = 0; i < 8; i++) m = fmaxf(m, red[t][i]);
    mfin[t] = m;
  }
  __syncthreads();
  // ---- exp + row sum ----
  float rowm[2][4], vsum[2][4];
#pragma unroll
  for (int mt = 0; mt < 2; mt++)
#pragma unroll
    for (int r = 0; r < 4; r++) {
      rowm[mt][r] = mfin[mt * 16 + quad * 4 + r];
      vsum[mt][r] = 0.f;
    }
#pragma unroll
  for (int mt = 0; mt < 2; mt++)
#pragma unroll
    for (int nt = 0; nt < 16; nt++)
#pragma unroll
      for (int r = 0; r < 4; r++) {
        float p = __expf(acc[mt][nt][r] - rowm[mt][r]);
        acc[mt][nt][r] = p;
        vsum[mt][r] += p;
      }
#pragma unroll
  for (int mt = 0; mt < 2; mt++)
#pragma unroll
    for (int r = 0; r < 4; r++) {
#pragma unroll
      for (int off = 1; off < 16; off <<= 1) vsum[mt][r] += __shfl_xor(vsum[mt][r], off);
    }
  __syncthreads();   // red[] reuse
  if (l16 == 0) {
#pragma unroll
    for (int mt = 0; mt < 2; mt++)
#pragma unroll
      for (int r = 0; r < 4; r++) red[mt * 16 + quad * 4 + r][w] = vsum[mt][r];
  }
  __syncthreads();
  if (t < 32) {
    float s = 0.f;
#pragma unroll
    for (int i = 0; i < 8; i++) s += red[t][i];
    linv_g[(size_t)b * Nn + q0 + t] = 1.f / s;
  }
  // ---- write P (unnormalized) bf16 ----
#pragma unroll
  for (int mt = 0; mt < 2; mt++)
#pragma unroll
    for (int nt = 0; nt < 16; nt++) {
      const size_t base = ((size_t)(b * Nn + q0 + mt * 16 + quad * 4)) * Nn + w * 256 + nt * 16 + l16;
#pragma unroll
      for (int r = 0; r < 4; r++)
        Pw[base + (size_t)r * Nn] = f2bf(acc[mt][nt][r]);
    }
}

// ---- pv_gemm (R4): delta = P @ X as m97-recipe GEMM. 128x128 tile, BK=64,
// 256 threads (4 waves, each 64x64), global_load_lds width-16 staging,
// ds_read_b128 frags, 32 MFMA/wave/k-step. Epilogue y = x + linv[m]*delta.
// XCD pin: b = (id&7)>>1, n-half = id&1 -> per-XCD Xt slice 2 MB (L2-resident).
__global__ __launch_bounds__(256, 2) void pv_gemm(
    const u16* __restrict__ Pw, const u16* __restrict__ xt,
    const float* __restrict__ x, const float* __restrict__ linv_g,
    float* __restrict__ y) {
  __shared__ u16 As[128 * 64];   // [row m][k] row-major, rows 128 B
  __shared__ u16 Bs[128 * 64];   // [col n(d)][k] row-major (Xt is d-major)
  const int t = threadIdx.x;
  const int w = t >> 6, l = t & 63, quad = l >> 4, l16 = l & 15;
  const int id = blockIdx.x;
  const int xcd = id & 7;
  const int b = xcd >> 1;
  const int nh = xcd & 1;
  const int rest = id >> 3;             // 0..63
  const int m0 = (rest & 15) * 128;     // 16 m-tiles
  const int n0 = (nh * 4 + (rest >> 4)) * 128;  // 8 n-tiles
  const int srow = w * 32 + (l >> 3);   // staging row base (per call +8)
  const int skoff = (l & 7) * 8;        // staging k offset (elements)
  f32x4 acc[4][4];
#pragma unroll
  for (int i = 0; i < 4; i++)
#pragma unroll
    for (int j = 0; j < 4; j++) acc[i][j] = (f32x4){0.f, 0.f, 0.f, 0.f};
  const int wm = w & 1, wn = w >> 1;
  for (int k0 = 0; k0 < Nn; k0 += 64) {
    __syncthreads();   // previous compute done before LDS overwrite
#pragma unroll
    for (int c = 0; c < 4; c++) {
      int row = srow + c * 8;
      g2l16(&As[(w * 32 + c * 8) * 64],
            &Pw[((size_t)(b * Nn + m0 + row)) * Nn + k0 + skoff]);
      g2l16(&Bs[(w * 32 + c * 8) * 64],
            &xt[((size_t)(b * Dd + n0 + row)) * Nn + k0 + skoff]);
    }
    __syncthreads();   // drains vmcnt(0) then barrier
#pragma unroll
    for (int ks = 0; ks < 2; ks++) {
      bf16x8 af[4], bf_[4];
#pragma unroll
      for (int mt = 0; mt < 4; mt++)
        af[mt] = *(const bf16x8*)&As[(wm * 64 + mt * 16 + l16) * 64 + ks * 32 + quad * 8];
#pragma unroll
      for (int nt = 0; nt < 4; nt++)
        bf_[nt] = *(const bf16x8*)&Bs[(wn * 64 + nt * 16 + l16) * 64 + ks * 32 + quad * 8];
#pragma unroll
      for (int mt = 0; mt < 4; mt++)
#pragma unroll
        for (int nt = 0; nt < 4; nt++)
          acc[mt][nt] = __builtin_amdgcn_mfma_f32_16x16x32_bf16(af[mt], bf_[nt], acc[mt][nt], 0, 0, 0);
    }
  }
  // ---- epilogue: y = x + linv[m] * delta ----
  float li[4][4];
#pragma unroll
  for (int mt = 0; mt < 4; mt++)
#pragma unroll
    for (int r = 0; r < 4; r++)
      li[mt][r] = linv_g[(size_t)b * Nn + m0 + wm * 64 + mt * 16 + quad * 4 + r];
#pragma unroll
  for (int mt = 0; mt < 4; mt++)
#pragma unroll
    for (int nt = 0; nt < 4; nt++) {
      const int nn = n0 + wn * 64 + nt * 16 + l16;
#pragma unroll
      for (int r = 0; r < 4; r++) {
        const int m = m0 + wm * 64 + mt * 16 + quad * 4 + r;
        const size_t off = ((size_t)(b * Nn + m)) * Dd + nn;
        y[off] = x[off] + li[mt][r] * acc[mt][nt][r];
      }
    }
}

// ---- ln_k: in-place row-wise LayerNorm over d_out. 1 block (256 thr) per row ----
__global__ __launch_bounds__(256) void ln_k(float* __restrict__ y,
    const float* __restrict__ gamma, const float* __restrict__ beta) {
  __shared__ float rs[4], rq[4];
  const int row = blockIdx.x;
  const int t = threadIdx.x;
  float* p = y + (size_t)row * Dd;
  float4 v = ((const float4*)p)[t];
  float s = v.x + v.y + v.z + v.w;
  float q = v.x * v.x + v.y * v.y + v.z * v.z + v.w * v.w;
#pragma unroll
  for (int off = 32; off; off >>= 1) {
    s += __shfl_xor(s, off);
    q += __shfl_xor(q, off);
  }
  if ((t & 63) == 0) { rs[t >> 6] = s; rq[t >> 6] = q; }
  __syncthreads();
  float S = rs[0] + rs[1] + rs[2] + rs[3];
  float Q2 = rq[0] + rq[1] + rq[2] + rq[3];
  float mu = S * (1.f / Dd);
  float var = Q2 * (1.f / Dd) - mu * mu;
  float rstd = rsqrtf(var + LN_EPS);
  float4 g = ((const float4*)gamma)[t];
  float4 be = ((const float4*)beta)[t];
  v.x = (v.x - mu) * rstd * g.x + be.x;
  v.y = (v.y - mu) * rstd * g.y + be.y;
  v.z = (v.z - mu) * rstd * g.z + be.z;
  v.w = (v.w - mu) * rstd * g.w + be.w;
  ((float4*)p)[t] = v;
}

extern "C" void kernel_launch(void* const* d_in, const int* in_sizes, int n_in,
                              void* d_out, int out_size, void* d_ws, size_t ws_size,
                              hipStream_t stream) {
  const float* x     = (const float*)d_in[0];
  const float* mask  = (const float*)d_in[1];
  const float* U     = (const float*)d_in[2];
  const float* V     = (const float*)d_in[3];
  const float* gamma = (const float*)d_in[4];
  const float* beta  = (const float*)d_in[5];
  float* out = (float*)d_out;
  char* ws = (char*)d_ws;
  // workspace layout (51 MB total)
  u16*   xt   = (u16*)ws;                                        // 16 MB (B,D,N) bf16
  u16*   Qw   = (u16*)(ws + (size_t)(16 << 20));                 // 1 MB
  u16*   Kw   = (u16*)(ws + (size_t)(17 << 20));                 // 1 MB
  u16*   uvt  = (u16*)(ws + (size_t)(18 << 20));                 // 256 KB
  float* qsb  = (float*)(ws + (size_t)(18 << 20) + (256 << 10)); // 32 KB
  float* linv = (float*)(ws + (size_t)(18 << 20) + (288 << 10)); // 32 KB
  u16*   Pw   = (u16*)(ws + (size_t)(19 << 20));                 // 32 MB (B,N,N) bf16

  prep_x       <<<dim3(Nn / 64, Dd / 64, Bb), 256, 0, stream>>>(x, xt);
  prep_small   <<<32 + (Bb * Nn) / 4, 256, 0, stream>>>(U, V, mask, uvt, qsb);
  proj_qk      <<<(Bb * Nn) / 64, 256, 0, stream>>>(x, mask, uvt, Qw, Kw);
  score_softmax<<<Bb * (Nn / 32), 512, 0, stream>>>(Qw, Kw, qsb, Pw, linv);
  pv_gemm      <<<Bb * (Nn / 128) * (Dd / 128), 256, 0, stream>>>(Pw, xt, x, linv, out);
  ln_k         <<<Bb * Nn, 256, 0, stream>>>(out, gamma, beta);
}

// Round 6
// 188.214 us; speedup vs baseline: 1.5634x; 1.1588x over previous
//
#include <hip/hip_runtime.h>

#define Bb 4
#define Nn 2048
#define Dd 1024
#define Rr 64
#define LN_EPS 1e-5f

typedef unsigned short u16;
typedef short bf16x8 __attribute__((ext_vector_type(8)));   // 8 bf16 in 4 VGPRs
typedef float f32x4 __attribute__((ext_vector_type(4)));

__device__ __forceinline__ u16 f2bf(float f) {
  unsigned u = __float_as_uint(f);
  u += 0x7FFFu + ((u >> 16) & 1u);   // RNE
  return (u16)(u >> 16);
}

// async global->LDS, 16 B per lane. LDS dest is wave-uniform base + lane*16.
__device__ __forceinline__ void g2l16(u16* l, const u16* g) {
  __builtin_amdgcn_global_load_lds(
      (const __attribute__((address_space(1))) unsigned int*)g,
      (__attribute__((address_space(3))) unsigned int*)l, 16, 0, 0);
}

// ---- prep_x: x (B,N,D) f32 -> xt (B,D,N) bf16 (d-major, pv_gemm B-operand) ----
__global__ __launch_bounds__(256) void prep_x(const float* __restrict__ x,
                                              u16* __restrict__ xt) {
  __shared__ float tile[64][65];
  const int b = blockIdx.z;
  const int n0 = blockIdx.x * 64;
  const int d0 = blockIdx.y * 64;
  const int t = threadIdx.x;
  const int c = t & 63, r4 = t >> 6;
#pragma unroll
  for (int rr = 0; rr < 16; rr++) {
    int row = rr * 4 + r4;
    tile[row][c] = x[(size_t)(b * Nn + n0 + row) * Dd + d0 + c];
  }
  __syncthreads();
#pragma unroll
  for (int rr = 0; rr < 16; rr++) {
    int dd = rr * 4 + r4;
    xt[(size_t)(b * Dd + d0 + dd) * Nn + n0 + c] = f2bf(tile[c][dd]);
  }
}

// ---- prep_small: fuses prep_uv (blocks 0..31) and qscale (blocks 32..2079) ----
__global__ __launch_bounds__(256) void prep_small(const float* __restrict__ U,
    const float* __restrict__ V, const float* __restrict__ mask,
    u16* __restrict__ uvt, float* __restrict__ qs) {
  if (blockIdx.x < 32) {
    __shared__ float tile[64][65];
    const int which = blockIdx.x >> 4;
    const int d0 = (blockIdx.x & 15) * 64;
    const float* src = which ? V : U;
    const int t = threadIdx.x, c = t & 63, r4 = t >> 6;
#pragma unroll
    for (int rr = 0; rr < 16; rr++) {
      int row = rr * 4 + r4;
      tile[row][c] = src[(size_t)(d0 + row) * Rr + c];
    }
    __syncthreads();
#pragma unroll
    for (int rr = 0; rr < 16; rr++) {
      int r = rr * 4 + r4;
      uvt[(size_t)(which * 64 + r) * Dd + d0 + c] = f2bf(tile[c][r]);
    }
  } else {
    const int row = (blockIdx.x - 32) * 4 + (threadIdx.x >> 6);
    const int lane = threadIdx.x & 63;
    float v = mask[(size_t)row * Rr + lane];
#pragma unroll
    for (int off = 32; off; off >>= 1) v += __shfl_xor(v, off);
    if (lane == 0) qs[row] = rsqrtf(fmaxf(v, 1.0f));
  }
}

// ---- proj_qk: Q = (x@U)*mask, K = (x@V)*mask, bf16 out.
// R5: 32 rows x 128 cols/block (grid 256 — R4's 128 blocks used half the CUs).
__global__ __launch_bounds__(256) void proj_qk(const float* __restrict__ x,
    const float* __restrict__ mask, const u16* __restrict__ uvt,
    u16* __restrict__ Qo, u16* __restrict__ Ko) {
  const int t = threadIdx.x;
  const int w = t >> 6, l = t & 63, quad = l >> 4, l16 = l & 15;
  const int g0 = blockIdx.x * 32;
  f32x4 acc[2][2];
#pragma unroll
  for (int i = 0; i < 2; i++)
#pragma unroll
    for (int j = 0; j < 2; j++) acc[i][j] = (f32x4){0.f, 0.f, 0.f, 0.f};
  for (int k0 = 0; k0 < Dd; k0 += 32) {
    bf16x8 a[2];
#pragma unroll
    for (int mt = 0; mt < 2; mt++) {
      const float4* px = (const float4*)&x[(size_t)(g0 + mt * 16 + l16) * Dd + k0 + quad * 8];
      float4 x0 = px[0], x1 = px[1];
      bf16x8 av;
      av[0] = (short)f2bf(x0.x); av[1] = (short)f2bf(x0.y);
      av[2] = (short)f2bf(x0.z); av[3] = (short)f2bf(x0.w);
      av[4] = (short)f2bf(x1.x); av[5] = (short)f2bf(x1.y);
      av[6] = (short)f2bf(x1.z); av[7] = (short)f2bf(x1.w);
      a[mt] = av;
    }
    bf16x8 bfr[2];
#pragma unroll
    for (int i = 0; i < 2; i++) {
      int col = (w * 2 + i) * 16 + l16;
      bfr[i] = *(const bf16x8*)&uvt[(size_t)col * Dd + k0 + quad * 8];
    }
#pragma unroll
    for (int mt = 0; mt < 2; mt++)
#pragma unroll
      for (int i = 0; i < 2; i++)
        acc[mt][i] = __builtin_amdgcn_mfma_f32_16x16x32_bf16(a[mt], bfr[i], acc[mt][i], 0, 0, 0);
  }
#pragma unroll
  for (int mt = 0; mt < 2; mt++)
#pragma unroll
    for (int i = 0; i < 2; i++) {
      int col = (w * 2 + i) * 16 + l16;
      int r_ = col & 63;
#pragma unroll
      for (int r = 0; r < 4; r++) {
        int row = g0 + mt * 16 + quad * 4 + r;
        float v = acc[mt][i][r] * mask[(size_t)row * Rr + r_];
        u16 bv = f2bf(v);
        if (col < 64) Qo[(size_t)row * Rr + r_] = bv;
        else          Ko[(size_t)row * Rr + r_] = bv;
      }
    }
}

// ---- score_softmax: block = 32 q-rows x ALL 2048 keys, 8 waves.
// Whole-row softmax once per block. Writes P = exp(v - rowmax) bf16
// (unnormalized) and linv = 1/rowsum.
__global__ __launch_bounds__(512, 2) void score_softmax(
    const u16* __restrict__ Qm, const u16* __restrict__ Km,
    const float* __restrict__ qs, u16* __restrict__ Pw,
    float* __restrict__ linv_g) {
  __shared__ float red[32][8];
  __shared__ float mfin[32];
  const int t = threadIdx.x;
  const int w = t >> 6, l = t & 63, quad = l >> 4, l16 = l & 15;
  const int id = blockIdx.x;
  const int xcd = id & 7;
  const int b = xcd >> 1;
  const int q0 = (((id >> 3) << 1) | (xcd & 1)) * 32;
  bf16x8 qf[2][2];
#pragma unroll
  for (int mt = 0; mt < 2; mt++)
#pragma unroll
    for (int ks = 0; ks < 2; ks++)
      qf[mt][ks] = *(const bf16x8*)&Qm[(size_t)(b * Nn + q0 + mt * 16 + l16) * Rr + ks * 32 + quad * 8];
  f32x4 acc[2][16];
#pragma unroll
  for (int mt = 0; mt < 2; mt++)
#pragma unroll
    for (int nt = 0; nt < 16; nt++) acc[mt][nt] = (f32x4){0.f, 0.f, 0.f, 0.f};
#pragma unroll
  for (int nt = 0; nt < 16; nt++) {
#pragma unroll
    for (int ks = 0; ks < 2; ks++) {
      bf16x8 kf = *(const bf16x8*)&Km[(size_t)(b * Nn + w * 256 + nt * 16 + l16) * Rr + ks * 32 + quad * 8];
#pragma unroll
      for (int mt = 0; mt < 2; mt++)
        acc[mt][nt] = __builtin_amdgcn_mfma_f32_16x16x32_bf16(qf[mt][ks], kf, acc[mt][nt], 0, 0, 0);
    }
  }
  float sc[2][4];
#pragma unroll
  for (int mt = 0; mt < 2; mt++)
#pragma unroll
    for (int r = 0; r < 4; r++)
      sc[mt][r] = qs[(size_t)b * Nn + q0 + mt * 16 + quad * 4 + r];
#pragma unroll
  for (int mt = 0; mt < 2; mt++)
#pragma unroll
    for (int nt = 0; nt < 16; nt++)
#pragma unroll
      for (int r = 0; r < 4; r++) acc[mt][nt][r] *= sc[mt][r];
  float vmax[2][4];
#pragma unroll
  for (int mt = 0; mt < 2; mt++)
#pragma unroll
    for (int r = 0; r < 4; r++) {
      float m = -1e30f;
#pragma unroll
      for (int nt = 0; nt < 16; nt++) m = fmaxf(m, acc[mt][nt][r]);
#pragma unroll
      for (int off = 1; off < 16; off <<= 1) m = fmaxf(m, __shfl_xor(m, off));
      vmax[mt][r] = m;
    }
  if (l16 == 0) {
#pragma unroll
    for (int mt = 0; mt < 2; mt++)
#pragma unroll
      for (int r = 0; r < 4; r++) red[mt * 16 + quad * 4 + r][w] = vmax[mt][r];
  }
  __syncthreads();
  if (t < 32) {
    float m = -1e30f;
#pragma unroll
    for (int i = 0; i < 8; i++) m = fmaxf(m, red[t][i]);
    mfin[t] = m;
  }
  __syncthreads();
  float rowm[2][4], vsum[2][4];
#pragma unroll
  for (int mt = 0; mt < 2; mt++)
#pragma unroll
    for (int r = 0; r < 4; r++) {
      rowm[mt][r] = mfin[mt * 16 + quad * 4 + r];
      vsum[mt][r] = 0.f;
    }
#pragma unroll
  for (int mt = 0; mt < 2; mt++)
#pragma unroll
    for (int nt = 0; nt < 16; nt++)
#pragma unroll
      for (int r = 0; r < 4; r++) {
        float p = __expf(acc[mt][nt][r] - rowm[mt][r]);
        acc[mt][nt][r] = p;
        vsum[mt][r] += p;
      }
#pragma unroll
  for (int mt = 0; mt < 2; mt++)
#pragma unroll
    for (int r = 0; r < 4; r++) {
#pragma unroll
      for (int off = 1; off < 16; off <<= 1) vsum[mt][r] += __shfl_xor(vsum[mt][r], off);
    }
  __syncthreads();   // red[] reuse
  if (l16 == 0) {
#pragma unroll
    for (int mt = 0; mt < 2; mt++)
#pragma unroll
      for (int r = 0; r < 4; r++) red[mt * 16 + quad * 4 + r][w] = vsum[mt][r];
  }
  __syncthreads();
  if (t < 32) {
    float s = 0.f;
#pragma unroll
    for (int i = 0; i < 8; i++) s += red[t][i];
    linv_g[(size_t)b * Nn + q0 + t] = 1.f / s;
  }
#pragma unroll
  for (int mt = 0; mt < 2; mt++)
#pragma unroll
    for (int nt = 0; nt < 16; nt++) {
      const size_t base = ((size_t)(b * Nn + q0 + mt * 16 + quad * 4)) * Nn + w * 256 + nt * 16 + l16;
#pragma unroll
      for (int r = 0; r < 4; r++)
        Pw[base + (size_t)r * Nn] = f2bf(acc[mt][nt][r]);
    }
}

// ---- pv_gemm: delta = P @ X, m97-recipe GEMM. 128x128 tile, BK=64.
// R5: XOR-swizzled LDS k-chunks. Row stride is 64 u16 = 128 B = 32 banks, so
// the naive frag read (16 rows, same k-offset) was ~16-way conflicted
// (SQ_LDS_BANK_CONFLICT 1.26e7 ~= 20 us/dispatch). Staging lane l now fetches
// global k-chunk (l&7)^((l>>3)&7) — same 128 B span per 8-lane row-group, so
// global coalescing is unchanged and the LDS dest stays lane*16-contiguous —
// and frag reads use slot = (ks*4+quad)^(row&7): 8 distinct 16 B bank-groups,
// 2 lanes each = 2-way = free (m136).
__global__ __launch_bounds__(256, 2) void pv_gemm(
    const u16* __restrict__ Pw, const u16* __restrict__ xt,
    const float* __restrict__ x, const float* __restrict__ linv_g,
    float* __restrict__ y) {
  __shared__ u16 As[128 * 64];   // [row m][k-slot] swizzled
  __shared__ u16 Bs[128 * 64];   // [col n(d)][k-slot] swizzled
  const int t = threadIdx.x;
  const int w = t >> 6, l = t & 63, quad = l >> 4, l16 = l & 15;
  const int id = blockIdx.x;
  const int xcd = id & 7;
  const int b = xcd >> 1;
  const int nh = xcd & 1;
  const int rest = id >> 3;             // 0..63
  const int m0 = (rest & 15) * 128;     // 16 m-tiles
  const int n0 = (nh * 4 + (rest >> 4)) * 128;  // 8 n-tiles
  const int srow = w * 32 + (l >> 3);   // staging row base (per call +8)
  const int skoff = (((l & 7) ^ ((l >> 3) & 7)) * 8);  // swizzled global k-chunk
  f32x4 acc[4][4];
#pragma unroll
  for (int i = 0; i < 4; i++)
#pragma unroll
    for (int j = 0; j < 4; j++) acc[i][j] = (f32x4){0.f, 0.f, 0.f, 0.f};
  const int wm = w & 1, wn = w >> 1;
  // per-lane swizzled frag slots (row&7 == l16&7 for both A and B reads)
  const int sw = (l16 & 7);
  for (int k0 = 0; k0 < Nn; k0 += 64) {
    __syncthreads();   // previous compute done before LDS overwrite
#pragma unroll
    for (int c = 0; c < 4; c++) {
      int row = srow + c * 8;
      g2l16(&As[(w * 32 + c * 8) * 64],
            &Pw[((size_t)(b * Nn + m0 + row)) * Nn + k0 + skoff]);
      g2l16(&Bs[(w * 32 + c * 8) * 64],
            &xt[((size_t)(b * Dd + n0 + row)) * Nn + k0 + skoff]);
    }
    __syncthreads();   // drains vmcnt(0) then barrier
#pragma unroll
    for (int ks = 0; ks < 2; ks++) {
      const int slot = ((ks * 4 + quad) ^ sw) * 8;
      bf16x8 af[4], bf_[4];
#pragma unroll
      for (int mt = 0; mt < 4; mt++)
        af[mt] = *(const bf16x8*)&As[(wm * 64 + mt * 16 + l16) * 64 + slot];
#pragma unroll
      for (int nt = 0; nt < 4; nt++)
        bf_[nt] = *(const bf16x8*)&Bs[(wn * 64 + nt * 16 + l16) * 64 + slot];
#pragma unroll
      for (int mt = 0; mt < 4; mt++)
#pragma unroll
        for (int nt = 0; nt < 4; nt++)
          acc[mt][nt] = __builtin_amdgcn_mfma_f32_16x16x32_bf16(af[mt], bf_[nt], acc[mt][nt], 0, 0, 0);
    }
  }
  // ---- epilogue: y = x + linv[m] * delta ----
  float li[4][4];
#pragma unroll
  for (int mt = 0; mt < 4; mt++)
#pragma unroll
    for (int r = 0; r < 4; r++)
      li[mt][r] = linv_g[(size_t)b * Nn + m0 + wm * 64 + mt * 16 + quad * 4 + r];
#pragma unroll
  for (int mt = 0; mt < 4; mt++)
#pragma unroll
    for (int nt = 0; nt < 4; nt++) {
      const int nn = n0 + wn * 64 + nt * 16 + l16;
#pragma unroll
      for (int r = 0; r < 4; r++) {
        const int m = m0 + wm * 64 + mt * 16 + quad * 4 + r;
        const size_t off = ((size_t)(b * Nn + m)) * Dd + nn;
        y[off] = x[off] + li[mt][r] * acc[mt][nt][r];
      }
    }
}

// ---- ln_k: in-place row-wise LayerNorm over d_out. 1 block (256 thr) per row ----
__global__ __launch_bounds__(256) void ln_k(float* __restrict__ y,
    const float* __restrict__ gamma, const float* __restrict__ beta) {
  __shared__ float rs[4], rq[4];
  const int row = blockIdx.x;
  const int t = threadIdx.x;
  float* p = y + (size_t)row * Dd;
  float4 v = ((const float4*)p)[t];
  float s = v.x + v.y + v.z + v.w;
  float q = v.x * v.x + v.y * v.y + v.z * v.z + v.w * v.w;
#pragma unroll
  for (int off = 32; off; off >>= 1) {
    s += __shfl_xor(s, off);
    q += __shfl_xor(q, off);
  }
  if ((t & 63) == 0) { rs[t >> 6] = s; rq[t >> 6] = q; }
  __syncthreads();
  float S = rs[0] + rs[1] + rs[2] + rs[3];
  float Q2 = rq[0] + rq[1] + rq[2] + rq[3];
  float mu = S * (1.f / Dd);
  float var = Q2 * (1.f / Dd) - mu * mu;
  float rstd = rsqrtf(var + LN_EPS);
  float4 g = ((const float4*)gamma)[t];
  float4 be = ((const float4*)beta)[t];
  v.x = (v.x - mu) * rstd * g.x + be.x;
  v.y = (v.y - mu) * rstd * g.y + be.y;
  v.z = (v.z - mu) * rstd * g.z + be.z;
  v.w = (v.w - mu) * rstd * g.w + be.w;
  ((float4*)p)[t] = v;
}

extern "C" void kernel_launch(void* const* d_in, const int* in_sizes, int n_in,
                              void* d_out, int out_size, void* d_ws, size_t ws_size,
                              hipStream_t stream) {
  const float* x     = (const float*)d_in[0];
  const float* mask  = (const float*)d_in[1];
  const float* U     = (const float*)d_in[2];
  const float* V     = (const float*)d_in[3];
  const float* gamma = (const float*)d_in[4];
  const float* beta  = (const float*)d_in[5];
  float* out = (float*)d_out;
  char* ws = (char*)d_ws;
  // workspace layout (51 MB total)
  u16*   xt   = (u16*)ws;                                        // 16 MB (B,D,N) bf16
  u16*   Qw   = (u16*)(ws + (size_t)(16 << 20));                 // 1 MB
  u16*   Kw   = (u16*)(ws + (size_t)(17 << 20));                 // 1 MB
  u16*   uvt  = (u16*)(ws + (size_t)(18 << 20));                 // 256 KB
  float* qsb  = (float*)(ws + (size_t)(18 << 20) + (256 << 10)); // 32 KB
  float* linv = (float*)(ws + (size_t)(18 << 20) + (288 << 10)); // 32 KB
  u16*   Pw   = (u16*)(ws + (size_t)(19 << 20));                 // 32 MB (B,N,N) bf16

  prep_x       <<<dim3(Nn / 64, Dd / 64, Bb), 256, 0, stream>>>(x, xt);
  prep_small   <<<32 + (Bb * Nn) / 4, 256, 0, stream>>>(U, V, mask, uvt, qsb);
  proj_qk      <<<(Bb * Nn) / 32, 256, 0, stream>>>(x, mask, uvt, Qw, Kw);
  score_softmax<<<Bb * (Nn / 32), 512, 0, stream>>>(Qw, Kw, qsb, Pw, linv);
  pv_gemm      <<<Bb * (Nn / 128) * (Dd / 128), 256, 0, stream>>>(Pw, xt, x, linv, out);
  ln_k         <<<Bb * Nn, 256, 0, stream>>>(out, gamma, beta);
}